// Round 3
// baseline (11754.300 us; speedup 1.0000x reference)
//
#include <hip/hip_runtime.h>
#include <cstddef>

#define B_ 256
#define T_ 128
#define F_ 256
#define H_ 512
#define C_ 10

#define TEAMS 16     // teams of blocks; team owns BS batch rows
#define TB    16     // blocks per team; member owns NS output columns
#define BS    16     // batch rows per team
#define NS    32     // n columns per member block

// ---------------------------------------------------------------------------
// GEMM: Cout[M, 512] = A[M, K] @ W[512, K]^T + b1 + b2   (fp32, vector ALU)
// ---------------------------------------------------------------------------
template<int K>
__global__ __launch_bounds__(256) void gemm_bias_kernel(
    const float* __restrict__ A, const float* __restrict__ W,
    const float* __restrict__ b1, const float* __restrict__ b2,
    float* __restrict__ Cout)
{
    __shared__ alignas(16) float As[32][68];
    __shared__ alignas(16) float Ws[32][132];

    const int tid = threadIdx.x;
    const int m0 = blockIdx.x * 64;
    const int n0 = blockIdx.y * 128;
    const int tx = tid & 15;
    const int ty = tid >> 4;

    float acc[4][8];
#pragma unroll
    for (int i = 0; i < 4; i++)
#pragma unroll
        for (int j = 0; j < 8; j++) acc[i][j] = 0.f;

    for (int k0 = 0; k0 < K; k0 += 32) {
#pragma unroll
        for (int i = 0; i < 2; i++) {
            int f = tid + 256 * i;
            int m = f >> 3, k4 = (f & 7) * 4;
            float4 v = *(const float4*)(A + (size_t)(m0 + m) * K + k0 + k4);
            As[k4 + 0][m] = v.x; As[k4 + 1][m] = v.y;
            As[k4 + 2][m] = v.z; As[k4 + 3][m] = v.w;
        }
#pragma unroll
        for (int i = 0; i < 4; i++) {
            int f = tid + 256 * i;
            int n = f >> 3, k4 = (f & 7) * 4;
            float4 v = *(const float4*)(W + (size_t)(n0 + n) * K + k0 + k4);
            Ws[k4 + 0][n] = v.x; Ws[k4 + 1][n] = v.y;
            Ws[k4 + 2][n] = v.z; Ws[k4 + 3][n] = v.w;
        }
        __syncthreads();

#pragma unroll 8
        for (int kk = 0; kk < 32; kk++) {
            float4 a4 = *(const float4*)&As[kk][ty * 4];
            float4 w0 = *(const float4*)&Ws[kk][tx * 8];
            float4 w1 = *(const float4*)&Ws[kk][tx * 8 + 4];
            float a[4] = {a4.x, a4.y, a4.z, a4.w};
            float w[8] = {w0.x, w0.y, w0.z, w0.w, w1.x, w1.y, w1.z, w1.w};
#pragma unroll
            for (int i = 0; i < 4; i++)
#pragma unroll
                for (int j = 0; j < 8; j++)
                    acc[i][j] = fmaf(a[i], w[j], acc[i][j]);
        }
        __syncthreads();
    }

    float bias[8];
#pragma unroll
    for (int j = 0; j < 8; j++) {
        int n = n0 + tx * 8 + j;
        bias[j] = b1[n] + b2[n];
    }
#pragma unroll
    for (int i = 0; i < 4; i++) {
        int m = m0 + ty * 4 + i;
        float4 v0 = {acc[i][0] + bias[0], acc[i][1] + bias[1],
                     acc[i][2] + bias[2], acc[i][3] + bias[3]};
        float4 v1 = {acc[i][4] + bias[4], acc[i][5] + bias[5],
                     acc[i][6] + bias[6], acc[i][7] + bias[7]};
        *(float4*)(Cout + (size_t)m * H_ + n0 + tx * 8)     = v0;
        *(float4*)(Cout + (size_t)m * H_ + n0 + tx * 8 + 4) = v1;
    }
}

// ---------------------------------------------------------------------------
// Team-parallel recurrent scan, fp32, W_hh register-stationary.
//
// Grid = TEAMS*TB = 256 blocks x 256 threads (1/CU; 48KB LDS + ~110 VGPR =>
// every CU can host >=2 blocks, so all 256 blocks are co-resident and the
// team spin-barrier cannot deadlock).
//
// Block (team, mem): batch rows [team*BS, +BS), columns [mem*NS, +NS).
// Thread (nl = tid&31, kg = tid>>5): holds W[n0+nl][kg*64 .. +63] in 16
// float4 registers for the entire scan. Per step: stage h_prev[BS][512]
// into LDS (coalesced), compute BS k-partial dots (LDS broadcast reads,
// conflict-free), reduce 8 k-groups via LDS, add proj, ReLU, write h in
// place into data[b][t][n], then team-barrier on a monotonic device-scope
// counter (targets offset by gen0 so layer 1 continues layer 0's counts).
// ---------------------------------------------------------------------------
__global__ __launch_bounds__(256, 1) void scan_team_kernel(
    float* __restrict__ data, const float* __restrict__ Whh,
    unsigned int* __restrict__ bar, int gen0)
{
    __shared__ alignas(16) float hs[BS][H_];        // 32 KB
    __shared__ alignas(16) float red[8][BS][NS];    // 16 KB

    const int tid  = threadIdx.x;
    const int team = blockIdx.x >> 4;
    const int mem  = blockIdx.x & 15;
    const int b0   = team * BS;
    const int n0   = mem * NS;
    const int nl   = tid & 31;
    const int kg   = tid >> 5;          // 0..7, k-slice of 64
    const int n    = n0 + nl;

    // W slice -> 16 float4 regs (one-time load)
    float4 w[16];
    const float* wrow = Whh + (size_t)n * H_ + kg * 64;
#pragma unroll
    for (int j = 0; j < 16; j++) w[j] = *(const float4*)(wrow + j * 4);

    for (int t = 0; t < T_; t++) {
        // ---- stage h_{t-1} rows (this team's rows only) ----
        if (t == 0) {
#pragma unroll
            for (int i = 0; i < 8; i++) {
                int f = tid + 256 * i;                 // float4 index into hs
                ((float4*)hs)[f] = float4{0.f, 0.f, 0.f, 0.f};
            }
        } else {
#pragma unroll
            for (int i = 0; i < 8; i++) {
                int f = tid + 256 * i;
                int b = f >> 7;                        // 128 float4 per row
                int c = f & 127;
                ((float4*)hs)[f] = *(const float4*)(
                    data + ((size_t)(b0 + b) * T_ + (t - 1)) * H_ + c * 4);
            }
        }
        __syncthreads();

        // ---- k-partial dot products: p[b] = sum_{k in kg slice} W[n][k] h[b][k]
        float p[BS];
#pragma unroll
        for (int b = 0; b < BS; b++) p[b] = 0.f;
#pragma unroll
        for (int j = 0; j < 16; j++) {
            const float4 wv = w[j];
            const int kb = kg * 64 + j * 4;
#pragma unroll
            for (int b = 0; b < BS; b++) {
                float4 hv = *(const float4*)&hs[b][kb];  // broadcast read
                p[b] = fmaf(wv.x, hv.x, fmaf(wv.y, hv.y,
                       fmaf(wv.z, hv.z, fmaf(wv.w, hv.w, p[b]))));
            }
        }

        // ---- reduce 8 k-groups through LDS ----
#pragma unroll
        for (int b = 0; b < BS; b++) red[kg][b][nl] = p[b];
        __syncthreads();

#pragma unroll
        for (int i = 0; i < 2; i++) {
            int o  = tid + 256 * i;                    // 512 outputs per block
            int b  = o >> 5;
            int n2 = o & 31;
            float s = red[0][b][n2] + red[1][b][n2] + red[2][b][n2] + red[3][b][n2]
                    + red[4][b][n2] + red[5][b][n2] + red[6][b][n2] + red[7][b][n2];
            size_t idx = ((size_t)(b0 + b) * T_ + t) * H_ + n0 + n2;
            float h = fmaxf(s + data[idx], 0.f);       // + proj, ReLU
            data[idx] = h;                              // in-place h_t
        }

        // ---- team barrier (skip after final step; gen0 accounts across layers)
        if (t < T_ - 1) {
            __threadfence();          // release this thread's h stores (agent)
            __syncthreads();
            if (tid == 0) {
                __hip_atomic_fetch_add(bar + team, 1u,
                                       __ATOMIC_RELEASE, __HIP_MEMORY_SCOPE_AGENT);
                const unsigned target = (unsigned)TB * (unsigned)(gen0 + t + 1);
                while (__hip_atomic_load(bar + team,
                                         __ATOMIC_ACQUIRE, __HIP_MEMORY_SCOPE_AGENT)
                       < target) {
                    __builtin_amdgcn_s_sleep(8);
                }
                __threadfence();      // acquire: invalidate caches before re-reads
            }
            __syncthreads();
        }
    }
}

// ---------------------------------------------------------------------------
// FC head: out[b][c] = sum_i h1[b][i] * Wfc[c][i] + bfc[c]
// ---------------------------------------------------------------------------
__global__ __launch_bounds__(256) void fc_kernel(
    const float* __restrict__ Hl, const float* __restrict__ Wfc,
    const float* __restrict__ bfc, float* __restrict__ out)
{
    const int b = blockIdx.x;
    const int tid = threadIdx.x;
    const float* hb = Hl + (size_t)b * (T_ * H_);

    float acc[C_];
#pragma unroll
    for (int c = 0; c < C_; c++) acc[c] = 0.f;

    for (int i = tid * 4; i < T_ * H_; i += 256 * 4) {
        float4 hv = *(const float4*)(hb + i);
#pragma unroll
        for (int c = 0; c < C_; c++) {
            float4 wv = *(const float4*)(Wfc + (size_t)c * (T_ * H_) + i);
            acc[c] = fmaf(hv.x, wv.x, fmaf(hv.y, wv.y,
                     fmaf(hv.z, wv.z, fmaf(hv.w, wv.w, acc[c]))));
        }
    }

    __shared__ float red[4][C_];
#pragma unroll
    for (int c = 0; c < C_; c++) {
        float v = acc[c];
#pragma unroll
        for (int off = 32; off >= 1; off >>= 1) v += __shfl_xor(v, off, 64);
        if ((tid & 63) == 0) red[tid >> 6][c] = v;
    }
    __syncthreads();
    if (tid < C_) {
        float v = red[0][tid] + red[1][tid] + red[2][tid] + red[3][tid] + bfc[tid];
        out[(size_t)b * C_ + tid] = v;
    }
}

// ---------------------------------------------------------------------------
// Pipeline: proj0 GEMM -> scan0 -> proj1 GEMM -> scan1 -> FC.
// Team-barrier counters live in the first 64B of d_out (zeroed via
// hipMemsetAsync, graph-safe; fully overwritten by fc_kernel at the end).
// Both scans share one monotonic counter per team: scan0 targets
// TB*(t+1) ending at TB*127 (last step skips the barrier), scan1 uses
// gen0=127 so its targets continue at TB*(128+t).
// ---------------------------------------------------------------------------
extern "C" void kernel_launch(void* const* d_in, const int* in_sizes, int n_in,
                              void* d_out, int out_size, void* d_ws, size_t ws_size,
                              hipStream_t stream)
{
    (void)in_sizes; (void)n_in; (void)out_size; (void)ws_size;

    const float* x    = (const float*)d_in[0];
    const float* Wih0 = (const float*)d_in[1];
    const float* Whh0 = (const float*)d_in[2];
    const float* bih0 = (const float*)d_in[3];
    const float* bhh0 = (const float*)d_in[4];
    const float* Wih1 = (const float*)d_in[5];
    const float* Whh1 = (const float*)d_in[6];
    const float* bih1 = (const float*)d_in[7];
    const float* bhh1 = (const float*)d_in[8];
    const float* Wfc  = (const float*)d_in[9];
    const float* bfc  = (const float*)d_in[10];
    float* out = (float*)d_out;

    float* ws0 = (float*)d_ws;                    // [B][T][H] proj0 -> h0
    float* ws1 = ws0 + (size_t)B_ * T_ * H_;      // [B][T][H] proj1 -> h1
    unsigned int* bar = (unsigned int*)d_out;     // TEAMS counters, 64 B

    hipMemsetAsync(bar, 0, TEAMS * sizeof(unsigned int), stream);

    dim3 gproj(B_ * T_ / 64, H_ / 128);

    gemm_bias_kernel<F_><<<gproj, 256, 0, stream>>>(x, Wih0, bih0, bhh0, ws0);
    scan_team_kernel<<<TEAMS * TB, 256, 0, stream>>>(ws0, Whh0, bar, 0);

    gemm_bias_kernel<H_><<<gproj, 256, 0, stream>>>(ws0, Wih1, bih1, bhh1, ws1);
    scan_team_kernel<<<TEAMS * TB, 256, 0, stream>>>(ws1, Whh1, bar, T_ - 1);

    fc_kernel<<<B_, 256, 0, stream>>>(ws1, Wfc, bfc, out);
}

// Round 4
// 3469.773 us; speedup vs baseline: 3.3876x; 3.3876x over previous
//
#include <hip/hip_runtime.h>
#include <cstddef>

#define B_ 256
#define T_ 128
#define F_ 256
#define H_ 512
#define C_ 10

#define TEAMS 16     // teams of blocks; team owns BS batch rows
#define TB    16     // blocks per team; member owns NS output columns
#define BS    16     // batch rows per team
#define NS    32     // n columns per member block

// ---------------------------------------------------------------------------
// GEMM: Cout[M, 512] = A[M, K] @ W[512, K]^T + b1 + b2   (fp32, vector ALU)
// ---------------------------------------------------------------------------
template<int K>
__global__ __launch_bounds__(256) void gemm_bias_kernel(
    const float* __restrict__ A, const float* __restrict__ W,
    const float* __restrict__ b1, const float* __restrict__ b2,
    float* __restrict__ Cout)
{
    __shared__ alignas(16) float As[32][68];
    __shared__ alignas(16) float Ws[32][132];

    const int tid = threadIdx.x;
    const int m0 = blockIdx.x * 64;
    const int n0 = blockIdx.y * 128;
    const int tx = tid & 15;
    const int ty = tid >> 4;

    float acc[4][8];
#pragma unroll
    for (int i = 0; i < 4; i++)
#pragma unroll
        for (int j = 0; j < 8; j++) acc[i][j] = 0.f;

    for (int k0 = 0; k0 < K; k0 += 32) {
#pragma unroll
        for (int i = 0; i < 2; i++) {
            int f = tid + 256 * i;
            int m = f >> 3, k4 = (f & 7) * 4;
            float4 v = *(const float4*)(A + (size_t)(m0 + m) * K + k0 + k4);
            As[k4 + 0][m] = v.x; As[k4 + 1][m] = v.y;
            As[k4 + 2][m] = v.z; As[k4 + 3][m] = v.w;
        }
#pragma unroll
        for (int i = 0; i < 4; i++) {
            int f = tid + 256 * i;
            int n = f >> 3, k4 = (f & 7) * 4;
            float4 v = *(const float4*)(W + (size_t)(n0 + n) * K + k0 + k4);
            Ws[k4 + 0][n] = v.x; Ws[k4 + 1][n] = v.y;
            Ws[k4 + 2][n] = v.z; Ws[k4 + 3][n] = v.w;
        }
        __syncthreads();

#pragma unroll 8
        for (int kk = 0; kk < 32; kk++) {
            float4 a4 = *(const float4*)&As[kk][ty * 4];
            float4 w0 = *(const float4*)&Ws[kk][tx * 8];
            float4 w1 = *(const float4*)&Ws[kk][tx * 8 + 4];
            float a[4] = {a4.x, a4.y, a4.z, a4.w};
            float w[8] = {w0.x, w0.y, w0.z, w0.w, w1.x, w1.y, w1.z, w1.w};
#pragma unroll
            for (int i = 0; i < 4; i++)
#pragma unroll
                for (int j = 0; j < 8; j++)
                    acc[i][j] = fmaf(a[i], w[j], acc[i][j]);
        }
        __syncthreads();
    }

    float bias[8];
#pragma unroll
    for (int j = 0; j < 8; j++) {
        int n = n0 + tx * 8 + j;
        bias[j] = b1[n] + b2[n];
    }
#pragma unroll
    for (int i = 0; i < 4; i++) {
        int m = m0 + ty * 4 + i;
        float4 v0 = {acc[i][0] + bias[0], acc[i][1] + bias[1],
                     acc[i][2] + bias[2], acc[i][3] + bias[3]};
        float4 v1 = {acc[i][4] + bias[4], acc[i][5] + bias[5],
                     acc[i][6] + bias[6], acc[i][7] + bias[7]};
        *(float4*)(Cout + (size_t)m * H_ + n0 + tx * 8)     = v0;
        *(float4*)(Cout + (size_t)m * H_ + n0 + tx * 8 + 4) = v1;
    }
}

// ---------------------------------------------------------------------------
// Team-parallel recurrent scan, fp32, W_hh register-stationary.
//
// Exchange transport (the round-3 fix): h values move through RELAXED
// agent-scope atomic loads/stores on `data` itself — no __threadfence, so
// no L2 writeback/invalidate storms. Visibility ordering: __syncthreads()
// compiles to s_waitcnt vmcnt(0) + s_barrier, so every wave's h-stores are
// globally visible (acked at the coherence point) before lane 0 signals
// the team counter. Counters are relaxed agent-scope atomics padded to one
// 64 B line per team. Team = blockIdx & 15 so members are congruent mod 8
// -> same XCD under the round-robin mapping (perf heuristic only).
//
// Grid = 256 blocks x 256 threads, 48 KB LDS, ~100 VGPR -> 1 block/CU,
// all 256 co-resident on 256 CUs => spin barrier cannot deadlock.
// ---------------------------------------------------------------------------
__global__ __launch_bounds__(256, 1) void scan_team_kernel(
    float* __restrict__ data, const float* __restrict__ Whh,
    unsigned int* __restrict__ bar, int gen0)
{
    __shared__ alignas(16) float hs[BS][H_];        // 32 KB
    __shared__ alignas(16) float red[8][BS][NS];    // 16 KB

    const int tid  = threadIdx.x;
    const int team = blockIdx.x & 15;   // same-XCD members (blk%8 heuristic)
    const int mem  = blockIdx.x >> 4;
    const int b0   = team * BS;
    const int n0   = mem * NS;
    const int nl   = tid & 31;
    const int kg   = tid >> 5;          // 0..7, k-slice of 64
    const int n    = n0 + nl;

    unsigned int* cnt = bar + team * 16;   // 64 B stride per team

    // W slice -> 16 float4 regs (one-time load, normal cached loads)
    float4 w[16];
    const float* wrow = Whh + (size_t)n * H_ + kg * 64;
#pragma unroll
    for (int j = 0; j < 16; j++) w[j] = *(const float4*)(wrow + j * 4);

    for (int t = 0; t < T_; t++) {
        // ---- stage h_{t-1} (this team's BS rows) into LDS ----
        if (t == 0) {
#pragma unroll
            for (int i = 0; i < 8; i++) {
                int f = tid + 256 * i;                 // float4 index
                ((float4*)hs)[f] = float4{0.f, 0.f, 0.f, 0.f};
            }
        } else {
            // 8192 dwords, 32/thread, coalesced; relaxed agent atomic loads
            // (bypass L1 -> always coherent with other members' stores)
#pragma unroll
            for (int i = 0; i < 32; i++) {
                int f = tid + 256 * i;
                int b = f >> 9;                        // 512 floats per row
                int c = f & 511;
                hs[b][c] = __hip_atomic_load(
                    data + ((size_t)(b0 + b) * T_ + (t - 1)) * H_ + c,
                    __ATOMIC_RELAXED, __HIP_MEMORY_SCOPE_AGENT);
            }
        }
        __syncthreads();

        // ---- k-partial dots: p[b] = sum_{k in kg slice} W[n][k] h[b][k] ----
        float p[BS];
#pragma unroll
        for (int b = 0; b < BS; b++) p[b] = 0.f;
#pragma unroll
        for (int j = 0; j < 16; j++) {
            const float4 wv = w[j];
            const int kb = kg * 64 + j * 4;
#pragma unroll
            for (int b = 0; b < BS; b++) {
                float4 hv = *(const float4*)&hs[b][kb];  // broadcast read
                p[b] = fmaf(wv.x, hv.x, fmaf(wv.y, hv.y,
                       fmaf(wv.z, hv.z, fmaf(wv.w, hv.w, p[b]))));
            }
        }

        // ---- reduce 8 k-groups through LDS ----
#pragma unroll
        for (int b = 0; b < BS; b++) red[kg][b][nl] = p[b];
        __syncthreads();

#pragma unroll
        for (int i = 0; i < 2; i++) {
            int o  = tid + 256 * i;                    // 512 outputs per block
            int b  = o >> 5;
            int n2 = o & 31;
            float s = red[0][b][n2] + red[1][b][n2] + red[2][b][n2] + red[3][b][n2]
                    + red[4][b][n2] + red[5][b][n2] + red[6][b][n2] + red[7][b][n2];
            size_t idx = ((size_t)(b0 + b) * T_ + t) * H_ + n0 + n2;
            float h = fmaxf(s + data[idx], 0.f);       // + proj (normal load), ReLU
            __hip_atomic_store(data + idx, h,          // h_t, coherent store
                               __ATOMIC_RELAXED, __HIP_MEMORY_SCOPE_AGENT);
        }

        // ---- team barrier (monotonic counter; gen0 continues across layers)
        if (t < T_ - 1) {
            __syncthreads();   // drains vmcnt(0): h-stores visible before signal
            if (tid == 0) {
                __hip_atomic_fetch_add(cnt, 1u,
                                       __ATOMIC_RELAXED, __HIP_MEMORY_SCOPE_AGENT);
                const unsigned target = (unsigned)TB * (unsigned)(gen0 + t + 1);
                while (__hip_atomic_load(cnt, __ATOMIC_RELAXED,
                                         __HIP_MEMORY_SCOPE_AGENT) < target) {
                    __builtin_amdgcn_s_sleep(2);
                }
            }
            __syncthreads();
        }
    }
}

// ---------------------------------------------------------------------------
// FC head: out[b][c] = sum_i h1[b][i] * Wfc[c][i] + bfc[c]
// ---------------------------------------------------------------------------
__global__ __launch_bounds__(256) void fc_kernel(
    const float* __restrict__ Hl, const float* __restrict__ Wfc,
    const float* __restrict__ bfc, float* __restrict__ out)
{
    const int b = blockIdx.x;
    const int tid = threadIdx.x;
    const float* hb = Hl + (size_t)b * (T_ * H_);

    float acc[C_];
#pragma unroll
    for (int c = 0; c < C_; c++) acc[c] = 0.f;

    for (int i = tid * 4; i < T_ * H_; i += 256 * 4) {
        float4 hv = *(const float4*)(hb + i);
#pragma unroll
        for (int c = 0; c < C_; c++) {
            float4 wv = *(const float4*)(Wfc + (size_t)c * (T_ * H_) + i);
            acc[c] = fmaf(hv.x, wv.x, fmaf(hv.y, wv.y,
                     fmaf(hv.z, wv.z, fmaf(hv.w, wv.w, acc[c]))));
        }
    }

    __shared__ float red[4][C_];
#pragma unroll
    for (int c = 0; c < C_; c++) {
        float v = acc[c];
#pragma unroll
        for (int off = 32; off >= 1; off >>= 1) v += __shfl_xor(v, off, 64);
        if ((tid & 63) == 0) red[tid >> 6][c] = v;
    }
    __syncthreads();
    if (tid < C_) {
        float v = red[0][tid] + red[1][tid] + red[2][tid] + red[3][tid] + bfc[tid];
        out[(size_t)b * C_ + tid] = v;
    }
}

// ---------------------------------------------------------------------------
// Pipeline: proj0 GEMM -> scan0 -> proj1 GEMM -> scan1 -> FC.
// Team counters: 16 teams x 64 B lines in the first 1 KB of d_out (zeroed by
// hipMemsetAsync — graph-safe; fc_kernel fully overwrites d_out at the end).
// Both scans share the monotonic counters: scan0 targets TB*(t+1) (last step
// skips the barrier, ending at TB*127), scan1 uses gen0=127 to continue.
// ---------------------------------------------------------------------------
extern "C" void kernel_launch(void* const* d_in, const int* in_sizes, int n_in,
                              void* d_out, int out_size, void* d_ws, size_t ws_size,
                              hipStream_t stream)
{
    (void)in_sizes; (void)n_in; (void)out_size; (void)ws_size;

    const float* x    = (const float*)d_in[0];
    const float* Wih0 = (const float*)d_in[1];
    const float* Whh0 = (const float*)d_in[2];
    const float* bih0 = (const float*)d_in[3];
    const float* bhh0 = (const float*)d_in[4];
    const float* Wih1 = (const float*)d_in[5];
    const float* Whh1 = (const float*)d_in[6];
    const float* bih1 = (const float*)d_in[7];
    const float* bhh1 = (const float*)d_in[8];
    const float* Wfc  = (const float*)d_in[9];
    const float* bfc  = (const float*)d_in[10];
    float* out = (float*)d_out;

    float* ws0 = (float*)d_ws;                    // [B][T][H] proj0 -> h0
    float* ws1 = ws0 + (size_t)B_ * T_ * H_;      // [B][T][H] proj1 -> h1
    unsigned int* bar = (unsigned int*)d_out;     // TEAMS x 16-dword lines

    hipMemsetAsync(bar, 0, TEAMS * 16 * sizeof(unsigned int), stream);

    dim3 gproj(B_ * T_ / 64, H_ / 128);

    gemm_bias_kernel<F_><<<gproj, 256, 0, stream>>>(x, Wih0, bih0, bhh0, ws0);
    scan_team_kernel<<<TEAMS * TB, 256, 0, stream>>>(ws0, Whh0, bar, 0);

    gemm_bias_kernel<H_><<<gproj, 256, 0, stream>>>(ws0, Wih1, bih1, bhh1, ws1);
    scan_team_kernel<<<TEAMS * TB, 256, 0, stream>>>(ws1, Whh1, bar, T_ - 1);

    fc_kernel<<<B_, 256, 0, stream>>>(ws1, Wfc, bfc, out);
}

// Round 5
// 1910.581 us; speedup vs baseline: 6.1522x; 1.8161x over previous
//
#include <hip/hip_runtime.h>
#include <cstddef>

#define B_ 256
#define T_ 128
#define F_ 256
#define H_ 512
#define C_ 10

#define TEAMS 32     // teams; team owns BS batch rows (2 teams co-resident/CU)
#define TB    16     // blocks per team; member owns NS output columns
#define BS    8      // batch rows per team
#define NS    32     // n columns per member block

// ---------------------------------------------------------------------------
// GEMM: Cout[M, 512] = A[M, K] @ W[512, K]^T + b1 + b2   (fp32, vector ALU)
// ---------------------------------------------------------------------------
template<int K>
__global__ __launch_bounds__(256) void gemm_bias_kernel(
    const float* __restrict__ A, const float* __restrict__ W,
    const float* __restrict__ b1, const float* __restrict__ b2,
    float* __restrict__ Cout)
{
    __shared__ alignas(16) float As[32][68];
    __shared__ alignas(16) float Ws[32][132];

    const int tid = threadIdx.x;
    const int m0 = blockIdx.x * 64;
    const int n0 = blockIdx.y * 128;
    const int tx = tid & 15;
    const int ty = tid >> 4;

    float acc[4][8];
#pragma unroll
    for (int i = 0; i < 4; i++)
#pragma unroll
        for (int j = 0; j < 8; j++) acc[i][j] = 0.f;

    for (int k0 = 0; k0 < K; k0 += 32) {
#pragma unroll
        for (int i = 0; i < 2; i++) {
            int f = tid + 256 * i;
            int m = f >> 3, k4 = (f & 7) * 4;
            float4 v = *(const float4*)(A + (size_t)(m0 + m) * K + k0 + k4);
            As[k4 + 0][m] = v.x; As[k4 + 1][m] = v.y;
            As[k4 + 2][m] = v.z; As[k4 + 3][m] = v.w;
        }
#pragma unroll
        for (int i = 0; i < 4; i++) {
            int f = tid + 256 * i;
            int n = f >> 3, k4 = (f & 7) * 4;
            float4 v = *(const float4*)(W + (size_t)(n0 + n) * K + k0 + k4);
            Ws[k4 + 0][n] = v.x; Ws[k4 + 1][n] = v.y;
            Ws[k4 + 2][n] = v.z; Ws[k4 + 3][n] = v.w;
        }
        __syncthreads();

#pragma unroll 8
        for (int kk = 0; kk < 32; kk++) {
            float4 a4 = *(const float4*)&As[kk][ty * 4];
            float4 w0 = *(const float4*)&Ws[kk][tx * 8];
            float4 w1 = *(const float4*)&Ws[kk][tx * 8 + 4];
            float a[4] = {a4.x, a4.y, a4.z, a4.w};
            float w[8] = {w0.x, w0.y, w0.z, w0.w, w1.x, w1.y, w1.z, w1.w};
#pragma unroll
            for (int i = 0; i < 4; i++)
#pragma unroll
                for (int j = 0; j < 8; j++)
                    acc[i][j] = fmaf(a[i], w[j], acc[i][j]);
        }
        __syncthreads();
    }

    float bias[8];
#pragma unroll
    for (int j = 0; j < 8; j++) {
        int n = n0 + tx * 8 + j;
        bias[j] = b1[n] + b2[n];
    }
#pragma unroll
    for (int i = 0; i < 4; i++) {
        int m = m0 + ty * 4 + i;
        float4 v0 = {acc[i][0] + bias[0], acc[i][1] + bias[1],
                     acc[i][2] + bias[2], acc[i][3] + bias[3]};
        float4 v1 = {acc[i][4] + bias[4], acc[i][5] + bias[5],
                     acc[i][6] + bias[6], acc[i][7] + bias[7]};
        *(float4*)(Cout + (size_t)m * H_ + n0 + tx * 8)     = v0;
        *(float4*)(Cout + (size_t)m * H_ + n0 + tx * 8 + 4) = v1;
    }
}

// ---------------------------------------------------------------------------
// Team-parallel recurrent scan, fp32, W_hh register-stationary.
//
// Transport (verified round 4): h moves via RELAXED agent-scope atomics on
// `data` (L1-bypassing, cross-XCD coherent, no cache-flush fences).
// __syncthreads() drains vmcnt(0) before s_barrier, so h-stores are globally
// visible before lane 0 signals the team counter.
//
// Round-5 changes:
//  * proj(t) prefetched at loop top (normal cached load: only the owning
//    block ever touches that line, read-before-own-write -> never stale),
//    overlapping its HBM latency with staging + compute.
//  * staging as 64-bit atomic loads (8/thread), incremental pointers.
//  * 32 teams x 16 blocks = 512 blocks, 2/CU: LDS 24 KB/block (cap 6/CU),
//    VGPR << 256 with __launch_bounds__(256,2) (cap >= 2/CU), so all 512
//    blocks are co-resident -> spin barrier cannot deadlock. Sibling blocks
//    are different teams: one team's barrier stalls hide under the other's
//    compute.
// ---------------------------------------------------------------------------
__global__ __launch_bounds__(256, 2) void scan_team_kernel(
    float* __restrict__ data, const float* __restrict__ Whh,
    unsigned int* __restrict__ bar, int gen0)
{
    __shared__ alignas(16) float hs[BS][H_];        // 16 KB
    __shared__ alignas(16) float red[8][BS][NS];    // 8 KB

    const int tid  = threadIdx.x;
    const int team = blockIdx.x & 31;   // members congruent mod 32 -> same XCD heuristic
    const int mem  = blockIdx.x >> 5;   // 0..15
    const int b0   = team * BS;
    const int n0   = mem * NS;
    const int nl   = tid & 31;
    const int kg   = tid >> 5;          // 0..7, k-slice of 64
    const int n    = n0 + nl;

    unsigned int* cnt = bar + team * 16;   // 64 B line per team

    // W slice -> 16 float4 regs (one-time load, normal cached loads)
    float4 w[16];
    const float* wrow = Whh + (size_t)n * H_ + kg * 64;
#pragma unroll
    for (int j = 0; j < 16; j++) w[j] = *(const float4*)(wrow + j * 4);

    // proj/h pointer for this thread's single output (b = tid>>5, col = n0+(tid&31))
    float* pptr = data + ((size_t)(b0 + (tid >> 5)) * T_) * H_ + n0 + (tid & 31);

    for (int t = 0; t < T_; t++) {
        // ---- prefetch proj(t) (off critical path; drains with staging) ----
        float projv = *pptr;

        // ---- stage h_{t-1} (team's BS rows) into LDS: 1 qword/thread/row ----
        if (t == 0) {
#pragma unroll
            for (int i = 0; i < 4; i++)
                ((float4*)hs)[tid + 256 * i] = float4{0.f, 0.f, 0.f, 0.f};
        } else {
            const float* sp = data + ((size_t)b0 * T_ + (t - 1)) * H_;
#pragma unroll
            for (int b = 0; b < BS; b++) {
                unsigned long long v = __hip_atomic_load(
                    (const unsigned long long*)(sp + (size_t)b * T_ * H_) + tid,
                    __ATOMIC_RELAXED, __HIP_MEMORY_SCOPE_AGENT);
                *((unsigned long long*)&hs[b][0] + tid) = v;
            }
        }
        __syncthreads();

        // ---- k-partial dots: p[b] = sum_{k in kg slice} W[n][k] h[b][k] ----
        float p[BS];
#pragma unroll
        for (int b = 0; b < BS; b++) p[b] = 0.f;
#pragma unroll
        for (int j = 0; j < 16; j++) {
            const float4 wv = w[j];
            const int kb = kg * 64 + j * 4;
#pragma unroll
            for (int b = 0; b < BS; b++) {
                float4 hv = *(const float4*)&hs[b][kb];  // broadcast read
                p[b] = fmaf(wv.x, hv.x, fmaf(wv.y, hv.y,
                       fmaf(wv.z, hv.z, fmaf(wv.w, hv.w, p[b]))));
            }
        }

        // ---- reduce 8 k-groups through LDS ----
#pragma unroll
        for (int b = 0; b < BS; b++) red[kg][b][nl] = p[b];
        __syncthreads();

        // ---- epilogue: 1 output/thread ----
        {
            int bb = tid >> 5, n2 = tid & 31;
            float s = red[0][bb][n2] + red[1][bb][n2] + red[2][bb][n2] + red[3][bb][n2]
                    + red[4][bb][n2] + red[5][bb][n2] + red[6][bb][n2] + red[7][bb][n2];
            float h = fmaxf(s + projv, 0.f);
            __hip_atomic_store(pptr, h,
                               __ATOMIC_RELAXED, __HIP_MEMORY_SCOPE_AGENT);
        }
        pptr += H_;

        // ---- team barrier (monotonic counter; gen0 continues across layers)
        if (t < T_ - 1) {
            __syncthreads();   // drains vmcnt(0): h-stores visible before signal
            if (tid == 0) {
                __hip_atomic_fetch_add(cnt, 1u,
                                       __ATOMIC_RELAXED, __HIP_MEMORY_SCOPE_AGENT);
                const unsigned target = (unsigned)TB * (unsigned)(gen0 + t + 1);
                while (__hip_atomic_load(cnt, __ATOMIC_RELAXED,
                                         __HIP_MEMORY_SCOPE_AGENT) < target) {
                    __builtin_amdgcn_s_sleep(2);
                }
            }
            __syncthreads();
        }
    }
}

// ---------------------------------------------------------------------------
// FC head: out[b][c] = sum_i h1[b][i] * Wfc[c][i] + bfc[c]
// ---------------------------------------------------------------------------
__global__ __launch_bounds__(256) void fc_kernel(
    const float* __restrict__ Hl, const float* __restrict__ Wfc,
    const float* __restrict__ bfc, float* __restrict__ out)
{
    const int b = blockIdx.x;
    const int tid = threadIdx.x;
    const float* hb = Hl + (size_t)b * (T_ * H_);

    float acc[C_];
#pragma unroll
    for (int c = 0; c < C_; c++) acc[c] = 0.f;

    for (int i = tid * 4; i < T_ * H_; i += 256 * 4) {
        float4 hv = *(const float4*)(hb + i);
#pragma unroll
        for (int c = 0; c < C_; c++) {
            float4 wv = *(const float4*)(Wfc + (size_t)c * (T_ * H_) + i);
            acc[c] = fmaf(hv.x, wv.x, fmaf(hv.y, wv.y,
                     fmaf(hv.z, wv.z, fmaf(hv.w, wv.w, acc[c]))));
        }
    }

    __shared__ float red[4][C_];
#pragma unroll
    for (int c = 0; c < C_; c++) {
        float v = acc[c];
#pragma unroll
        for (int off = 32; off >= 1; off >>= 1) v += __shfl_xor(v, off, 64);
        if ((tid & 63) == 0) red[tid >> 6][c] = v;
    }
    __syncthreads();
    if (tid < C_) {
        float v = red[0][tid] + red[1][tid] + red[2][tid] + red[3][tid] + bfc[tid];
        out[(size_t)b * C_ + tid] = v;
    }
}

// ---------------------------------------------------------------------------
// Pipeline: proj0 GEMM -> scan0 -> proj1 GEMM -> scan1 -> FC.
// Team counters: 32 teams x 64 B lines in the first 2 KB of d_out (zeroed by
// hipMemsetAsync — graph-safe; fc_kernel fully overwrites d_out at the end).
// Monotonic counters shared across both scans: scan0 targets TB*(t+1) (last
// step skips the barrier, ending at TB*127), scan1 uses gen0=127 to continue.
// ---------------------------------------------------------------------------
extern "C" void kernel_launch(void* const* d_in, const int* in_sizes, int n_in,
                              void* d_out, int out_size, void* d_ws, size_t ws_size,
                              hipStream_t stream)
{
    (void)in_sizes; (void)n_in; (void)out_size; (void)ws_size;

    const float* x    = (const float*)d_in[0];
    const float* Wih0 = (const float*)d_in[1];
    const float* Whh0 = (const float*)d_in[2];
    const float* bih0 = (const float*)d_in[3];
    const float* bhh0 = (const float*)d_in[4];
    const float* Wih1 = (const float*)d_in[5];
    const float* Whh1 = (const float*)d_in[6];
    const float* bih1 = (const float*)d_in[7];
    const float* bhh1 = (const float*)d_in[8];
    const float* Wfc  = (const float*)d_in[9];
    const float* bfc  = (const float*)d_in[10];
    float* out = (float*)d_out;

    float* ws0 = (float*)d_ws;                    // [B][T][H] proj0 -> h0
    float* ws1 = ws0 + (size_t)B_ * T_ * H_;      // [B][T][H] proj1 -> h1
    unsigned int* bar = (unsigned int*)d_out;     // TEAMS x 16-dword lines

    hipMemsetAsync(bar, 0, TEAMS * 16 * sizeof(unsigned int), stream);

    dim3 gproj(B_ * T_ / 64, H_ / 128);

    gemm_bias_kernel<F_><<<gproj, 256, 0, stream>>>(x, Wih0, bih0, bhh0, ws0);
    scan_team_kernel<<<TEAMS * TB, 256, 0, stream>>>(ws0, Whh0, bar, 0);

    gemm_bias_kernel<H_><<<gproj, 256, 0, stream>>>(ws0, Wih1, bih1, bhh1, ws1);
    scan_team_kernel<<<TEAMS * TB, 256, 0, stream>>>(ws1, Whh1, bar, T_ - 1);

    fc_kernel<<<B_, 256, 0, stream>>>(ws1, Wfc, bfc, out);
}

// Round 7
// 1906.753 us; speedup vs baseline: 6.1646x; 1.0020x over previous
//
#include <hip/hip_runtime.h>
#include <cstddef>

#define B_ 256
#define T_ 128
#define F_ 256
#define H_ 512
#define C_ 10

#define TEAMS 32     // teams; team owns BS batch rows (2 teams co-resident/CU)
#define TB    16     // blocks per team; member owns NS output columns
#define BS    8      // batch rows per team
#define NS    32     // n columns per member block

// ---------------------------------------------------------------------------
// GEMM: Cout[M, 512] = A[M, K] @ W[512, K]^T + b1 + b2   (fp32, vector ALU)
// ---------------------------------------------------------------------------
template<int K>
__global__ __launch_bounds__(256) void gemm_bias_kernel(
    const float* __restrict__ A, const float* __restrict__ W,
    const float* __restrict__ b1, const float* __restrict__ b2,
    float* __restrict__ Cout)
{
    __shared__ alignas(16) float As[32][68];
    __shared__ alignas(16) float Ws[32][132];

    const int tid = threadIdx.x;
    const int m0 = blockIdx.x * 64;
    const int n0 = blockIdx.y * 128;
    const int tx = tid & 15;
    const int ty = tid >> 4;

    float acc[4][8];
#pragma unroll
    for (int i = 0; i < 4; i++)
#pragma unroll
        for (int j = 0; j < 8; j++) acc[i][j] = 0.f;

    for (int k0 = 0; k0 < K; k0 += 32) {
#pragma unroll
        for (int i = 0; i < 2; i++) {
            int f = tid + 256 * i;
            int m = f >> 3, k4 = (f & 7) * 4;
            float4 v = *(const float4*)(A + (size_t)(m0 + m) * K + k0 + k4);
            As[k4 + 0][m] = v.x; As[k4 + 1][m] = v.y;
            As[k4 + 2][m] = v.z; As[k4 + 3][m] = v.w;
        }
#pragma unroll
        for (int i = 0; i < 4; i++) {
            int f = tid + 256 * i;
            int n = f >> 3, k4 = (f & 7) * 4;
            float4 v = *(const float4*)(W + (size_t)(n0 + n) * K + k0 + k4);
            Ws[k4 + 0][n] = v.x; Ws[k4 + 1][n] = v.y;
            Ws[k4 + 2][n] = v.z; Ws[k4 + 3][n] = v.w;
        }
        __syncthreads();

#pragma unroll 8
        for (int kk = 0; kk < 32; kk++) {
            float4 a4 = *(const float4*)&As[kk][ty * 4];
            float4 w0 = *(const float4*)&Ws[kk][tx * 8];
            float4 w1 = *(const float4*)&Ws[kk][tx * 8 + 4];
            float a[4] = {a4.x, a4.y, a4.z, a4.w};
            float w[8] = {w0.x, w0.y, w0.z, w0.w, w1.x, w1.y, w1.z, w1.w};
#pragma unroll
            for (int i = 0; i < 4; i++)
#pragma unroll
                for (int j = 0; j < 8; j++)
                    acc[i][j] = fmaf(a[i], w[j], acc[i][j]);
        }
        __syncthreads();
    }

    float bias[8];
#pragma unroll
    for (int j = 0; j < 8; j++) {
        int n = n0 + tx * 8 + j;
        bias[j] = b1[n] + b2[n];
    }
#pragma unroll
    for (int i = 0; i < 4; i++) {
        int m = m0 + ty * 4 + i;
        float4 v0 = {acc[i][0] + bias[0], acc[i][1] + bias[1],
                     acc[i][2] + bias[2], acc[i][3] + bias[3]};
        float4 v1 = {acc[i][4] + bias[4], acc[i][5] + bias[5],
                     acc[i][6] + bias[6], acc[i][7] + bias[7]};
        *(float4*)(Cout + (size_t)m * H_ + n0 + tx * 8)     = v0;
        *(float4*)(Cout + (size_t)m * H_ + n0 + tx * 8 + 4) = v1;
    }
}

// ---------------------------------------------------------------------------
// Team-parallel recurrent scan, fp32, W_hh register-stationary.
//
// Transport (verified r4/r5): h moves via RELAXED agent-scope atomics on
// `data` (L1-bypassing, coherent, no cache-flush fences). __syncthreads()
// drains vmcnt(0) before s_barrier, so h-stores are globally visible before
// lane 0 signals. Barrier: r5's proven monotonic fetch_add counter.
//
// Round-7 changes (conservative subset of r6):
//  * W pinned in VGPRs via relaxed atomic qword loads — LLVM cannot
//    rematerialize atomic loads, so no per-step W re-reads (r5's
//    VGPR_Count=60 proved w[16] was remat'd into 16 L2 loads/thread/step).
//    Loaded pairwise directly into w[j]: peak prologue pressure ~70 VGPR,
//    not 128 (r6's tmp[32] risked the (256,2) cap).
//  * proj(t+1) prefetch issued between barrier-signal and spin, consumed
//    next step — HBM latency hides under the barrier wait.
// ---------------------------------------------------------------------------
__global__ __launch_bounds__(256, 2) void scan_team_kernel(
    float* __restrict__ data, const float* __restrict__ Whh,
    unsigned int* __restrict__ bar, int gen0)
{
    __shared__ alignas(16) float hs[BS][H_];        // 16 KB
    __shared__ alignas(16) float red[8][BS][NS];    // 8 KB

    const int tid  = threadIdx.x;
    const int team = blockIdx.x & 31;   // members congruent mod 32 -> same XCD
    const int mem  = blockIdx.x >> 5;   // 0..15
    const int b0   = team * BS;
    const int n0   = mem * NS;
    const int nl   = tid & 31;
    const int kg   = tid >> 5;          // 0..7, k-slice of 64
    const int n    = n0 + nl;
    (void)mem;

    unsigned int* cnt = bar + team * 16;   // 64 B line per team

    // ---- W slice -> 16 float4 regs, pinned via atomic loads (no remat) ----
    float4 w[16];
    {
        const unsigned long long* wq =
            (const unsigned long long*)(Whh + (size_t)n * H_ + (size_t)kg * 64);
#pragma unroll
        for (int j = 0; j < 16; j++) {
            union { unsigned long long q[2]; float4 f; } u;
            u.q[0] = __hip_atomic_load(wq + 2 * j,     __ATOMIC_RELAXED,
                                       __HIP_MEMORY_SCOPE_AGENT);
            u.q[1] = __hip_atomic_load(wq + 2 * j + 1, __ATOMIC_RELAXED,
                                       __HIP_MEMORY_SCOPE_AGENT);
            w[j] = u.f;
        }
    }

    // proj/h pointer for this thread's single output per step
    float* pptr = data + ((size_t)(b0 + (tid >> 5)) * T_) * H_ + n0 + (tid & 31);
    float projv = *pptr;   // t=0 prefetch (normal cached load, owner-only line)

    for (int t = 0; t < T_; t++) {
        // ---- stage h_{t-1} (team's BS rows) into LDS: 1 qword/thread/row ----
        if (t == 0) {
#pragma unroll
            for (int i = 0; i < 4; i++)
                ((float4*)hs)[tid + 256 * i] = float4{0.f, 0.f, 0.f, 0.f};
        } else {
            const float* sp = data + ((size_t)b0 * T_ + (t - 1)) * H_;
#pragma unroll
            for (int b = 0; b < BS; b++) {
                unsigned long long v = __hip_atomic_load(
                    (const unsigned long long*)(sp + (size_t)b * T_ * H_) + tid,
                    __ATOMIC_RELAXED, __HIP_MEMORY_SCOPE_AGENT);
                *((unsigned long long*)&hs[b][0] + tid) = v;
            }
        }
        __syncthreads();

        // ---- k-partial dots: p[b] = sum_{k in kg slice} W[n][k] h[b][k] ----
        float p[BS];
#pragma unroll
        for (int b = 0; b < BS; b++) p[b] = 0.f;
#pragma unroll
        for (int j = 0; j < 16; j++) {
            const float4 wv = w[j];
            const int kb = kg * 64 + j * 4;
#pragma unroll
            for (int b = 0; b < BS; b++) {
                float4 hv = *(const float4*)&hs[b][kb];  // broadcast read
                p[b] = fmaf(wv.x, hv.x, fmaf(wv.y, hv.y,
                       fmaf(wv.z, hv.z, fmaf(wv.w, hv.w, p[b]))));
            }
        }

        // ---- reduce 8 k-groups through LDS ----
#pragma unroll
        for (int b = 0; b < BS; b++) red[kg][b][nl] = p[b];
        __syncthreads();

        // ---- epilogue: 1 output/thread ----
        {
            int bb = tid >> 5, n2 = tid & 31;
            float s = red[0][bb][n2] + red[1][bb][n2] + red[2][bb][n2] + red[3][bb][n2]
                    + red[4][bb][n2] + red[5][bb][n2] + red[6][bb][n2] + red[7][bb][n2];
            float h = fmaxf(s + projv, 0.f);
            __hip_atomic_store(pptr, h,
                               __ATOMIC_RELAXED, __HIP_MEMORY_SCOPE_AGENT);
        }
        pptr += H_;

        // ---- team barrier (r5-proven); proj(t+1) prefetch rides the spin ----
        if (t < T_ - 1) {
            __syncthreads();   // drains vmcnt(0): h-stores visible before signal
            if (tid == 0)
                __hip_atomic_fetch_add(cnt, 1u,
                                       __ATOMIC_RELAXED, __HIP_MEMORY_SCOPE_AGENT);
            float nextproj = *pptr;          // in flight during the spin
            if (tid == 0) {
                const unsigned target = (unsigned)TB * (unsigned)(gen0 + t + 1);
                while (__hip_atomic_load(cnt, __ATOMIC_RELAXED,
                                         __HIP_MEMORY_SCOPE_AGENT) < target) {
                    __builtin_amdgcn_s_sleep(2);
                }
            }
            __syncthreads();   // release block; prefetch drains here too
            projv = nextproj;
        }
    }
}

// ---------------------------------------------------------------------------
// FC head: out[b][c] = sum_i h1[b][i] * Wfc[c][i] + bfc[c]
// ---------------------------------------------------------------------------
__global__ __launch_bounds__(256) void fc_kernel(
    const float* __restrict__ Hl, const float* __restrict__ Wfc,
    const float* __restrict__ bfc, float* __restrict__ out)
{
    const int b = blockIdx.x;
    const int tid = threadIdx.x;
    const float* hb = Hl + (size_t)b * (T_ * H_);

    float acc[C_];
#pragma unroll
    for (int c = 0; c < C_; c++) acc[c] = 0.f;

    for (int i = tid * 4; i < T_ * H_; i += 256 * 4) {
        float4 hv = *(const float4*)(hb + i);
#pragma unroll
        for (int c = 0; c < C_; c++) {
            float4 wv = *(const float4*)(Wfc + (size_t)c * (T_ * H_) + i);
            acc[c] = fmaf(hv.x, wv.x, fmaf(hv.y, wv.y,
                     fmaf(hv.z, wv.z, fmaf(hv.w, wv.w, acc[c]))));
        }
    }

    __shared__ float red[4][C_];
#pragma unroll
    for (int c = 0; c < C_; c++) {
        float v = acc[c];
#pragma unroll
        for (int off = 32; off >= 1; off >>= 1) v += __shfl_xor(v, off, 64);
        if ((tid & 63) == 0) red[tid >> 6][c] = v;
    }
    __syncthreads();
    if (tid < C_) {
        float v = red[0][tid] + red[1][tid] + red[2][tid] + red[3][tid] + bfc[tid];
        out[(size_t)b * C_ + tid] = v;
    }
}

// ---------------------------------------------------------------------------
// Pipeline: proj0 GEMM -> scan0 -> proj1 GEMM -> scan1 -> FC.
// Team counters: 32 teams x 64 B lines in the first 2 KB of d_out (zeroed by
// hipMemsetAsync — graph-safe; fc_kernel fully overwrites d_out at the end).
// Monotonic counters shared across both scans: scan0 targets TB*(t+1) (last
// step skips the barrier, ending at TB*127), scan1 uses gen0=127 to continue.
// ---------------------------------------------------------------------------
extern "C" void kernel_launch(void* const* d_in, const int* in_sizes, int n_in,
                              void* d_out, int out_size, void* d_ws, size_t ws_size,
                              hipStream_t stream)
{
    (void)in_sizes; (void)n_in; (void)out_size; (void)ws_size;

    const float* x    = (const float*)d_in[0];
    const float* Wih0 = (const float*)d_in[1];
    const float* Whh0 = (const float*)d_in[2];
    const float* bih0 = (const float*)d_in[3];
    const float* bhh0 = (const float*)d_in[4];
    const float* Wih1 = (const float*)d_in[5];
    const float* Whh1 = (const float*)d_in[6];
    const float* bih1 = (const float*)d_in[7];
    const float* bhh1 = (const float*)d_in[8];
    const float* Wfc  = (const float*)d_in[9];
    const float* bfc  = (const float*)d_in[10];
    float* out = (float*)d_out;

    float* ws0 = (float*)d_ws;                    // [B][T][H] proj0 -> h0
    float* ws1 = ws0 + (size_t)B_ * T_ * H_;      // [B][T][H] proj1 -> h1
    unsigned int* bar = (unsigned int*)d_out;     // TEAMS x 16-dword lines

    hipMemsetAsync(bar, 0, TEAMS * 16 * sizeof(unsigned int), stream);

    dim3 gproj(B_ * T_ / 64, H_ / 128);

    gemm_bias_kernel<F_><<<gproj, 256, 0, stream>>>(x, Wih0, bih0, bhh0, ws0);
    scan_team_kernel<<<TEAMS * TB, 256, 0, stream>>>(ws0, Whh0, bar, 0);

    gemm_bias_kernel<H_><<<gproj, 256, 0, stream>>>(ws0, Wih1, bih1, bhh1, ws1);
    scan_team_kernel<<<TEAMS * TB, 256, 0, stream>>>(ws1, Whh1, bar, T_ - 1);

    fc_kernel<<<B_, 256, 0, stream>>>(ws1, Wfc, bfc, out);
}

// Round 9
// 1701.846 us; speedup vs baseline: 6.9068x; 1.1204x over previous
//
#include <hip/hip_runtime.h>
#include <cstddef>

#define B_ 256
#define T_ 128
#define F_ 256
#define H_ 512
#define C_ 10

#define TEAMS 32     // teams; team owns BS batch rows (2 blocks co-resident/CU)
#define TB    16     // blocks per team; member owns NS output columns
#define BS    8      // batch rows per team
#define NS    32     // n columns per member block

// ---------------------------------------------------------------------------
// GEMM: Cout[M, 512] = A[M, K] @ W[512, K]^T + b1 + b2   (fp32, vector ALU)
// BM=BN=128, BK=16, 256 threads, 8x8 micro-tile (FMA:ds_read = 16:1).
// Sync-free beyond __syncthreads; cannot hang.
// ---------------------------------------------------------------------------
template<int K>
__global__ __launch_bounds__(256, 2) void gemm_bias_kernel(
    const float* __restrict__ A, const float* __restrict__ W,
    const float* __restrict__ b1, const float* __restrict__ b2,
    float* __restrict__ Cout)
{
    __shared__ alignas(16) float As[16][132];
    __shared__ alignas(16) float Ws[16][132];

    const int tid = threadIdx.x;
    const int m0 = blockIdx.x * 128;
    const int n0 = blockIdx.y * 128;
    const int tx = tid & 15;        // n dim: 16 threads * 8
    const int ty = tid >> 4;        // m dim: 16 threads * 8

    float acc[8][8];
#pragma unroll
    for (int i = 0; i < 8; i++)
#pragma unroll
        for (int j = 0; j < 8; j++) acc[i][j] = 0.f;

    for (int k0 = 0; k0 < K; k0 += 16) {
        // A tile: 128 rows x 16 k = 512 float4, 2/thread, coalesced along k
#pragma unroll
        for (int i = 0; i < 2; i++) {
            int f = tid + 256 * i;
            int m = f >> 2, k4 = (f & 3) * 4;
            float4 v = *(const float4*)(A + (size_t)(m0 + m) * K + k0 + k4);
            As[k4 + 0][m] = v.x; As[k4 + 1][m] = v.y;
            As[k4 + 2][m] = v.z; As[k4 + 3][m] = v.w;
        }
        // W tile: 128 rows x 16 k = 512 float4, 2/thread
#pragma unroll
        for (int i = 0; i < 2; i++) {
            int f = tid + 256 * i;
            int n = f >> 2, k4 = (f & 3) * 4;
            float4 v = *(const float4*)(W + (size_t)(n0 + n) * K + k0 + k4);
            Ws[k4 + 0][n] = v.x; Ws[k4 + 1][n] = v.y;
            Ws[k4 + 2][n] = v.z; Ws[k4 + 3][n] = v.w;
        }
        __syncthreads();

#pragma unroll
        for (int kk = 0; kk < 16; kk++) {
            float4 a0 = *(const float4*)&As[kk][ty * 8];
            float4 a1 = *(const float4*)&As[kk][ty * 8 + 4];
            float4 w0 = *(const float4*)&Ws[kk][tx * 8];
            float4 w1 = *(const float4*)&Ws[kk][tx * 8 + 4];
            float a[8] = {a0.x, a0.y, a0.z, a0.w, a1.x, a1.y, a1.z, a1.w};
            float w[8] = {w0.x, w0.y, w0.z, w0.w, w1.x, w1.y, w1.z, w1.w};
#pragma unroll
            for (int i = 0; i < 8; i++)
#pragma unroll
                for (int j = 0; j < 8; j++)
                    acc[i][j] = fmaf(a[i], w[j], acc[i][j]);
        }
        __syncthreads();
    }

    float bias[8];
#pragma unroll
    for (int j = 0; j < 8; j++) {
        int n = n0 + tx * 8 + j;
        bias[j] = b1[n] + b2[n];
    }
#pragma unroll
    for (int i = 0; i < 8; i++) {
        int m = m0 + ty * 8 + i;
        float4 v0 = {acc[i][0] + bias[0], acc[i][1] + bias[1],
                     acc[i][2] + bias[2], acc[i][3] + bias[3]};
        float4 v1 = {acc[i][4] + bias[4], acc[i][5] + bias[5],
                     acc[i][6] + bias[6], acc[i][7] + bias[7]};
        *(float4*)(Cout + (size_t)m * H_ + n0 + tx * 8)     = v0;
        *(float4*)(Cout + (size_t)m * H_ + n0 + tx * 8 + 4) = v1;
    }
}

// ---------------------------------------------------------------------------
// Team-parallel recurrent scan, fp32, W_hh register-stationary.
//
// Transport (verified r4/r5/r7): h moves via RELAXED agent-scope atomics on
// `data`; __syncthreads() drains vmcnt(0) before s_barrier so h-stores are
// globally visible before lane 0 signals. Barrier: r5/r7-PROVEN monotonic
// fetch_add counter (the flag+ballot variant hung in r6 AND r8 — banned).
//
// Round-9 change (sync-free): thread remap (32 cols x 8 kg-of-64) ->
// (16 col-PAIRS x 16 kg-of-32). Each staged h float4 now feeds 2 output
// columns: 64 broadcast ds_read_b128/step/thread instead of 128, same
// 512 FMAs. W regs unchanged (2 rows x 32 k = 16 float4).
// ---------------------------------------------------------------------------
__global__ __launch_bounds__(256, 2) void scan_team_kernel(
    float* __restrict__ data, const float* __restrict__ Whh,
    unsigned int* __restrict__ bar, int gen0)
{
    __shared__ alignas(16) float hs[BS][H_];         // 16 KB
    __shared__ alignas(16) float red[16][BS][NS];    // 16 KB

    const int tid  = threadIdx.x;
    const int team = blockIdx.x & 31;   // members congruent mod 32 -> same XCD
    const int mem  = blockIdx.x >> 5;   // 0..15
    const int b0   = team * BS;
    const int n0   = mem * NS;
    const int nl2  = tid & 15;          // col-pair index: cols n0+2*nl2, +1
    const int kg   = tid >> 4;          // 0..15, k-slice of 32
    const int n    = n0 + nl2 * 2;
    (void)mem;

    unsigned int* cnt = bar + team * 16;   // 64 B line per team

    // ---- W slices (2 rows x 32 k) -> 16 float4, atomic-pinned (r7) ----
    float4 w0[8], w1[8];
    {
        const unsigned long long* q0 =
            (const unsigned long long*)(Whh + (size_t)n * H_ + (size_t)kg * 32);
        const unsigned long long* q1 =
            (const unsigned long long*)(Whh + (size_t)(n + 1) * H_ + (size_t)kg * 32);
#pragma unroll
        for (int j = 0; j < 8; j++) {
            union { unsigned long long q[2]; float4 f; } u;
            u.q[0] = __hip_atomic_load(q0 + 2 * j,     __ATOMIC_RELAXED,
                                       __HIP_MEMORY_SCOPE_AGENT);
            u.q[1] = __hip_atomic_load(q0 + 2 * j + 1, __ATOMIC_RELAXED,
                                       __HIP_MEMORY_SCOPE_AGENT);
            w0[j] = u.f;
            u.q[0] = __hip_atomic_load(q1 + 2 * j,     __ATOMIC_RELAXED,
                                       __HIP_MEMORY_SCOPE_AGENT);
            u.q[1] = __hip_atomic_load(q1 + 2 * j + 1, __ATOMIC_RELAXED,
                                       __HIP_MEMORY_SCOPE_AGENT);
            w1[j] = u.f;
        }
    }

    // proj/h pointer for this thread's single output per step
    float* pptr = data + ((size_t)(b0 + (tid >> 5)) * T_) * H_ + n0 + (tid & 31);
    float projv = *pptr;   // t=0 prefetch (owner-only line, normal cached load)

    for (int t = 0; t < T_; t++) {
        // ---- stage h_{t-1} (team's BS rows) into LDS: 1 qword/thread/row ----
        if (t == 0) {
#pragma unroll
            for (int i = 0; i < 4; i++)
                ((float4*)hs)[tid + 256 * i] = float4{0.f, 0.f, 0.f, 0.f};
        } else {
            const float* sp = data + ((size_t)b0 * T_ + (t - 1)) * H_;
#pragma unroll
            for (int b = 0; b < BS; b++) {
                unsigned long long v = __hip_atomic_load(
                    (const unsigned long long*)(sp + (size_t)b * T_ * H_) + tid,
                    __ATOMIC_RELAXED, __HIP_MEMORY_SCOPE_AGENT);
                *((unsigned long long*)&hs[b][0] + tid) = v;
            }
        }
        __syncthreads();

        // ---- k-partial dots, 2 cols/thread: each hv feeds 2 FMA4s ----
        float p0[BS], p1[BS];
#pragma unroll
        for (int b = 0; b < BS; b++) { p0[b] = 0.f; p1[b] = 0.f; }
#pragma unroll
        for (int j = 0; j < 8; j++) {
            const float4 wa = w0[j];
            const float4 wb = w1[j];
            const int kb = kg * 32 + j * 4;
#pragma unroll
            for (int b = 0; b < BS; b++) {
                float4 hv = *(const float4*)&hs[b][kb];  // broadcast read
                p0[b] = fmaf(wa.x, hv.x, fmaf(wa.y, hv.y,
                        fmaf(wa.z, hv.z, fmaf(wa.w, hv.w, p0[b]))));
                p1[b] = fmaf(wb.x, hv.x, fmaf(wb.y, hv.y,
                        fmaf(wb.z, hv.z, fmaf(wb.w, hv.w, p1[b]))));
            }
        }

        // ---- reduce 16 k-groups through LDS (paired float2 stores) ----
#pragma unroll
        for (int b = 0; b < BS; b++)
            *(float2*)&red[kg][b][nl2 * 2] = float2{p0[b], p1[b]};
        __syncthreads();

        // ---- epilogue: 1 output/thread ----
        {
            int bb = tid >> 5, n2 = tid & 31;
            float s = 0.f;
#pragma unroll
            for (int g = 0; g < 16; g++) s += red[g][bb][n2];
            float h = fmaxf(s + projv, 0.f);
            __hip_atomic_store(pptr, h,
                               __ATOMIC_RELAXED, __HIP_MEMORY_SCOPE_AGENT);
        }
        pptr += H_;

        // ---- team barrier (r5/r7-proven); proj(t+1) prefetch rides the spin
        if (t < T_ - 1) {
            __syncthreads();   // drains vmcnt(0): h-stores visible before signal
            if (tid == 0)
                __hip_atomic_fetch_add(cnt, 1u,
                                       __ATOMIC_RELAXED, __HIP_MEMORY_SCOPE_AGENT);
            float nextproj = *pptr;          // in flight during the spin
            if (tid == 0) {
                const unsigned target = (unsigned)TB * (unsigned)(gen0 + t + 1);
                while (__hip_atomic_load(cnt, __ATOMIC_RELAXED,
                                         __HIP_MEMORY_SCOPE_AGENT) < target) {
                    __builtin_amdgcn_s_sleep(2);
                }
            }
            __syncthreads();   // release block; prefetch drains here too
            projv = nextproj;
        }
    }
}

// ---------------------------------------------------------------------------
// FC head: out[b][c] = sum_i h1[b][i] * Wfc[c][i] + bfc[c]
// ---------------------------------------------------------------------------
__global__ __launch_bounds__(256) void fc_kernel(
    const float* __restrict__ Hl, const float* __restrict__ Wfc,
    const float* __restrict__ bfc, float* __restrict__ out)
{
    const int b = blockIdx.x;
    const int tid = threadIdx.x;
    const float* hb = Hl + (size_t)b * (T_ * H_);

    float acc[C_];
#pragma unroll
    for (int c = 0; c < C_; c++) acc[c] = 0.f;

    for (int i = tid * 4; i < T_ * H_; i += 256 * 4) {
        float4 hv = *(const float4*)(hb + i);
#pragma unroll
        for (int c = 0; c < C_; c++) {
            float4 wv = *(const float4*)(Wfc + (size_t)c * (T_ * H_) + i);
            acc[c] = fmaf(hv.x, wv.x, fmaf(hv.y, wv.y,
                     fmaf(hv.z, wv.z, fmaf(hv.w, wv.w, acc[c]))));
        }
    }

    __shared__ float red[4][C_];
#pragma unroll
    for (int c = 0; c < C_; c++) {
        float v = acc[c];
#pragma unroll
        for (int off = 32; off >= 1; off >>= 1) v += __shfl_xor(v, off, 64);
        if ((tid & 63) == 0) red[tid >> 6][c] = v;
    }
    __syncthreads();
    if (tid < C_) {
        float v = red[0][tid] + red[1][tid] + red[2][tid] + red[3][tid] + bfc[tid];
        out[(size_t)b * C_ + tid] = v;
    }
}

// ---------------------------------------------------------------------------
// Pipeline: proj0 GEMM -> scan0 -> proj1 GEMM -> scan1 -> FC.
// Team counters: 32 teams x 64 B lines in the first 2 KB of d_out (zeroed by
// hipMemsetAsync — graph-safe; fc_kernel fully overwrites d_out at the end).
// Monotonic counters shared across both scans: scan0 targets TB*(t+1) (last
// step skips the barrier, ending at TB*127), scan1 uses gen0=127 to continue.
// ---------------------------------------------------------------------------
extern "C" void kernel_launch(void* const* d_in, const int* in_sizes, int n_in,
                              void* d_out, int out_size, void* d_ws, size_t ws_size,
                              hipStream_t stream)
{
    (void)in_sizes; (void)n_in; (void)out_size; (void)ws_size;

    const float* x    = (const float*)d_in[0];
    const float* Wih0 = (const float*)d_in[1];
    const float* Whh0 = (const float*)d_in[2];
    const float* bih0 = (const float*)d_in[3];
    const float* bhh0 = (const float*)d_in[4];
    const float* Wih1 = (const float*)d_in[5];
    const float* Whh1 = (const float*)d_in[6];
    const float* bih1 = (const float*)d_in[7];
    const float* bhh1 = (const float*)d_in[8];
    const float* Wfc  = (const float*)d_in[9];
    const float* bfc  = (const float*)d_in[10];
    float* out = (float*)d_out;

    float* ws0 = (float*)d_ws;                    // [B][T][H] proj0 -> h0
    float* ws1 = ws0 + (size_t)B_ * T_ * H_;      // [B][T][H] proj1 -> h1
    unsigned int* bar = (unsigned int*)d_out;     // TEAMS x 16-dword lines

    hipMemsetAsync(bar, 0, TEAMS * 16 * sizeof(unsigned int), stream);

    dim3 gproj(B_ * T_ / 128, H_ / 128);   // (256, 4)

    gemm_bias_kernel<F_><<<gproj, 256, 0, stream>>>(x, Wih0, bih0, bhh0, ws0);
    scan_team_kernel<<<TEAMS * TB, 256, 0, stream>>>(ws0, Whh0, bar, 0);

    gemm_bias_kernel<H_><<<gproj, 256, 0, stream>>>(ws0, Wih1, bih1, bhh1, ws1);
    scan_team_kernel<<<TEAMS * TB, 256, 0, stream>>>(ws1, Whh1, bar, T_ - 1);

    fc_kernel<<<B_, 256, 0, stream>>>(ws1, Wfc, bfc, out);
}